// Round 1
// baseline (12578.412 us; speedup 1.0000x reference)
//
#include <hip/hip_runtime.h>

// ---------------------------------------------------------------------------
// SPCNNClassifier: conv1d(k5,p2)+BN+ReLU -> 3x BiLSTM(H=512) -> Linear(6) ->
// CRF NLL (mean over batch). B=16, T=1024, E=C=1024, H=512, L=6.
// R6 = R5 with the recurrence re-partitioned 64 WGs -> 16 WGs (2 dir x 8 WG,
// 512 thr, 64 units/WG). Same tagged-qword exchange protocol (proven), but
// 4x less coherent-path poll traffic per round and 8 (not 32) producers per
// direction -> shorter straggler tail on the per-step latency chain.
//  - wave = (gate, unit-half): afrag[2][16] bf16x8 (128 VGPR), 32 MFMA/step.
//  - consumer polls 8 qwords/thread (512/wave); stages direct to Hb[16][522].
//  - producer: same shfl pair-pack, 2 tagged 8B agent stores per cu-even lane.
//  - Gs gate slice 8KB/step double-buffered; XB [16][16][72] (16B-aligned
//    rows) flushed to xout every 16 steps.
// ---------------------------------------------------------------------------

typedef short bf16_t;
typedef __attribute__((ext_vector_type(8))) short bf16x8;
typedef __attribute__((ext_vector_type(4))) float f32x4;

__device__ __forceinline__ bf16_t f2b(float x) {
  unsigned u = __float_as_uint(x);
  unsigned r = (u + 0x7fffu + ((u >> 16) & 1u)) >> 16;   // RNE
  return (bf16_t)(unsigned short)r;
}
__device__ __forceinline__ float b2f(bf16_t b) {
  return __uint_as_float(((unsigned)(unsigned short)b) << 16);
}
__device__ __forceinline__ float blo(unsigned u) { return __uint_as_float(u << 16); }
__device__ __forceinline__ float bhi(unsigned u) { return __uint_as_float(u & 0xffff0000u); }

// ---------------- converts ----------------

__global__ void embed_pad_k(const float* __restrict__ E, bf16_t* __restrict__ P) {
  size_t i4 = ((size_t)blockIdx.x * 256 + threadIdx.x) * 4;
  if (i4 >= 16ul * 1028 * 1024) return;
  int e = (int)(i4 & 1023);
  size_t rest = i4 >> 10;
  int tp = (int)(rest % 1028);
  int b  = (int)(rest / 1028);
  bf16_t o[4];
  if (tp >= 2 && tp < 1026) {
    const float4 v = *(const float4*)(E + (((size_t)b * 1024 + (tp - 2)) * 1024 + e));
    o[0] = f2b(v.x); o[1] = f2b(v.y); o[2] = f2b(v.z); o[3] = f2b(v.w);
  } else {
    o[0] = o[1] = o[2] = o[3] = 0;
  }
  *(uint2*)(P + i4) = *(const uint2*)o;
}

__global__ void convw_cvt_k(const float* __restrict__ S, bf16_t* __restrict__ D) {
  int idx = blockIdx.x * 256 + threadIdx.x;
  if (idx >= 1024 * 1024) return;
  int c = idx >> 10, e = idx & 1023;
  const float* s = S + (size_t)idx * 5;
#pragma unroll
  for (int kk = 0; kk < 5; kk++) D[(size_t)c * 5120 + kk * 1024 + e] = f2b(s[kk]);
}

__global__ void bnfold_k(const float* cb, const float* g, const float* be,
                         const float* mn, const float* vr, float* a, float* dd) {
  int c = blockIdx.x * 256 + threadIdx.x;
  if (c < 1024) {
    float s = g[c] * rsqrtf(vr[c] + 1e-5f);
    a[c] = s;
    dd[c] = (cb[c] - mn[c]) * s + be[c];
  }
}

__global__ void wihcvt_k(const float* __restrict__ S, bf16_t* __restrict__ D) {
  size_t i = ((size_t)blockIdx.x * 256 + threadIdx.x) * 4;
  if (i >= 3ul * 2 * 2048 * 1024) return;
  float4 v = *(const float4*)(S + i);
  bf16_t o[4] = {f2b(v.x), f2b(v.y), f2b(v.z), f2b(v.w)};
  *(uint2*)(D + i) = *(const uint2*)o;
}

// ---------------- gates GEMM: D[m=t*16+b][n=g*512+j] -> G[t][j>>4][g][j'][b]
__global__ __launch_bounds__(256, 1) void gemm_gates(
    const bf16_t* __restrict__ A, const bf16_t* __restrict__ W,
    const float* __restrict__ bias0, const float* __restrict__ bias1,
    bf16_t* __restrict__ G) {
  const int tid = threadIdx.x;
  const int m0 = (blockIdx.x >> 4) * 128, n0 = (blockIdx.x & 15) * 128;
  __shared__ bf16_t As[128][72];
  __shared__ bf16_t Bs[128][72];
  const int wv = tid >> 6, ln = tid & 63;
  const int wm = (wv >> 1) * 64, wn = (wv & 1) * 64;
  const int lb = ln & 15, lq = ln >> 4;
  f32x4 acc[4][4] = {};
  for (int k0 = 0; k0 < 1024; k0 += 64) {
    __syncthreads();
#pragma unroll
    for (int i = 0; i < 4; i++) {
      int idx = tid + i * 256, r = idx >> 3, ch = idx & 7;
      *(uint4*)&As[r][ch * 8] = *(const uint4*)(A + (size_t)(m0 + r) * 1024 + k0 + ch * 8);
      *(uint4*)&Bs[r][ch * 8] = *(const uint4*)(W + (size_t)(n0 + r) * 1024 + k0 + ch * 8);
    }
    __syncthreads();
#pragma unroll
    for (int kk = 0; kk < 2; kk++) {
      bf16x8 af[4], bfr[4];
#pragma unroll
      for (int t = 0; t < 4; t++) {
        af[t]  = *(const bf16x8*)&As[wm + t * 16 + lb][kk * 32 + lq * 8];
        bfr[t] = *(const bf16x8*)&Bs[wn + t * 16 + lb][kk * 32 + lq * 8];
      }
#pragma unroll
      for (int mt = 0; mt < 4; mt++)
#pragma unroll
        for (int nt = 0; nt < 4; nt++)
          acc[mt][nt] = __builtin_amdgcn_mfma_f32_16x16x32_bf16(af[mt], bfr[nt], acc[mt][nt], 0, 0, 0);
    }
  }
#pragma unroll
  for (int mt = 0; mt < 4; mt++)
#pragma unroll
    for (int nt = 0; nt < 4; nt++) {
      int col = n0 + wn + nt * 16 + lb;          // g*512 + j
      int g = col >> 9, j = col & 511;
      int jb2 = j >> 4, jp = j & 15;
      float bs = bias0[col] + bias1[col];
      int row0 = m0 + wm + mt * 16;              // t*16, b = lq*4 + r
      int t = row0 >> 4;
      bf16_t tmp[4];
#pragma unroll
      for (int r = 0; r < 4; r++) tmp[r] = f2b(acc[mt][nt][r] + bs);
      size_t base = (((size_t)t * 32 + jb2) * 4 + g) * 256 + jp * 16 + lq * 4;
      *(uint2*)&G[base] = *(const uint2*)tmp;    // 4 consecutive b, 8B store
    }
}

// ---------------- conv1d implicit GEMM + BN + ReLU
__global__ __launch_bounds__(256, 1) void conv_gemm(
    const bf16_t* __restrict__ EP, const bf16_t* __restrict__ Wc,
    const float* __restrict__ bn_a, const float* __restrict__ bn_d,
    bf16_t* __restrict__ X) {
  const int tid = threadIdx.x;
  const int m0 = (blockIdx.x >> 3) * 128, n0 = (blockIdx.x & 7) * 128;
  __shared__ bf16_t As[128][72];
  __shared__ bf16_t Bs[128][72];
  const int wv = tid >> 6, ln = tid & 63;
  const int wm = (wv >> 1) * 64, wn = (wv & 1) * 64;
  const int lb = ln & 15, lq = ln >> 4;
  f32x4 acc[4][4] = {};
  for (int kk = 0; kk < 5; kk++) {
    for (int k0 = 0; k0 < 1024; k0 += 64) {
      __syncthreads();
#pragma unroll
      for (int i = 0; i < 4; i++) {
        int idx = tid + i * 256, r = idx >> 3, ch = idx & 7;
        int m = m0 + r;
        const bf16_t* ap = EP + ((size_t)((m & 15) * 1028 + (m >> 4) + kk)) * 1024 + k0 + ch * 8;
        *(uint4*)&As[r][ch * 8] = *(const uint4*)ap;
        *(uint4*)&Bs[r][ch * 8] = *(const uint4*)(Wc + (size_t)(n0 + r) * 5120 + kk * 1024 + k0 + ch * 8);
      }
      __syncthreads();
#pragma unroll
      for (int kq = 0; kq < 2; kq++) {
        bf16x8 af[4], bfr[4];
#pragma unroll
        for (int t = 0; t < 4; t++) {
          af[t]  = *(const bf16x8*)&As[wm + t * 16 + lb][kq * 32 + lq * 8];
          bfr[t] = *(const bf16x8*)&Bs[wn + t * 16 + lb][kq * 32 + lq * 8];
        }
#pragma unroll
        for (int mt = 0; mt < 4; mt++)
#pragma unroll
          for (int nt = 0; nt < 4; nt++)
            acc[mt][nt] = __builtin_amdgcn_mfma_f32_16x16x32_bf16(af[mt], bfr[nt], acc[mt][nt], 0, 0, 0);
      }
    }
  }
#pragma unroll
  for (int mt = 0; mt < 4; mt++)
#pragma unroll
    for (int nt = 0; nt < 4; nt++) {
      int col = n0 + wn + nt * 16 + lb;
      float sa = bn_a[col], sd = bn_d[col];
#pragma unroll
      for (int r = 0; r < 4; r++) {
        int row = m0 + wm + mt * 16 + lq * 4 + r;
        float v = fmaxf(acc[mt][nt][r] * sa + sd, 0.f);
        X[(size_t)row * 1024 + col] = f2b(v);
      }
    }
}

// ---------------- persistent BiLSTM recurrence
// grid = 16 WGs: d = blk&1, wg = blk>>1, j0 = wg*64. 512 thr = 8 waves.
// wave wv: gate = wv&3, unit-half u0 = (wv>>2)*32. Same tagged-qword hstT
// protocol as before: hstT[2buf][2dir][4096] qw = (tag<<32)|2xbf16, layout
// qword = pair*16 + b (pair = unit/2).
__global__ __launch_bounds__(512, 1) void rec_kernel(
    const float* __restrict__ Whh,               // [2][2048][512] f32
    const bf16_t* __restrict__ Gfw,              // [512 t][32 jb][4 g][16 j'][16 b]
    const bf16_t* __restrict__ Gbw,
    bf16_t* __restrict__ xout,                   // [1024][16][1024]
    unsigned long long* __restrict__ hstT,
    float* __restrict__ cst,                     // [2dir][16][512]
    int t0f, int t0b, int nsteps, int tag_base) {
  const int tid = threadIdx.x;
  const int d  = blockIdx.x & 1;
  const int wg = blockIdx.x >> 1;       // 0..7
  const int j0 = wg << 6;               // 64 units per WG
  const int wv = tid >> 6;              // 0..7
  const int ln = tid & 63;
  const int lb = ln & 15;
  const int lq = ln >> 4;
  const int gate = wv & 3;
  const int u0 = (wv >> 2) << 5;        // 0 or 32

  __shared__ bf16_t Hb[16][522];        // 261 dw row stride (==5 mod 32)
  __shared__ float  Ex[4][64][17];      // [gate][unit][batch]
  __shared__ bf16_t Gs[2][4096];        // gate slice dbuf: [4 jb][4 g][16 j'][16 b]
  __shared__ bf16_t XB[16][16][72];     // xout buffer [t'][b][j'], 16B-aligned rows

  // A fragments: wave (gate,u-half); rows = Whh[d*2048 + gate*512 + j0+u0+nt*16+lb]
  bf16x8 afrag[2][16];
#pragma unroll
  for (int nt = 0; nt < 2; nt++) {
    const float* wrow = Whh + ((size_t)(d * 2048 + gate * 512 + j0 + u0 + nt * 16 + lb)) * 512;
#pragma unroll
    for (int kk = 0; kk < 16; kk++) {
      const float* wp = wrow + kk * 32 + lq * 8;
      float4 va = *(const float4*)wp;
      float4 vb = *(const float4*)(wp + 4);
      bf16x8 fr;
      fr[0] = f2b(va.x); fr[1] = f2b(va.y); fr[2] = f2b(va.z); fr[3] = f2b(va.w);
      fr[4] = f2b(vb.x); fr[5] = f2b(vb.y); fr[6] = f2b(vb.z); fr[7] = f2b(vb.w);
      afrag[nt][kk] = fr;
    }
  }
  const int cb = tid & 15;              // batch
  const int cu = tid >> 4;              // unit 0..31 (items cu, cu+32)
  float creg0 = cst[((size_t)d * 16 + cb) * 512 + j0 + cu];
  float creg1 = cst[((size_t)d * 16 + cb) * 512 + j0 + cu + 32];
  const bf16_t* G = (d == 0) ? Gfw : Gbw;
  const int jb0 = j0 >> 4;              // 4 consecutive 16-unit blocks
  const int gc  = tid >> 7;             // gate-slice chunk 0..3
  const int go  = tid & 127;

  // preload gate slice for s=0 into Gs[0] (8 KB, 16B per thread)
  {
    const int trow = (d == 0) ? 0 : (nsteps - 1);
    *(uint4*)&Gs[0][gc * 1024 + go * 8] =
        *(const uint4*)(G + ((size_t)trow * 32 + jb0 + gc) * 1024 + go * 8);
  }

  for (int s = 0; s < nsteps; s++) {
    const int rb = (s & 1) ^ 1, wb = s & 1;
    const int t = (d == 0) ? (t0f + s) : (t0b + nsteps - 1 - s);
    // issue next step's gate load BEFORE the poll (latency hides under poll RT)
    uint4 gnext = {0, 0, 0, 0};
    if (s + 1 < nsteps) {
      const int trn = (d == 0) ? (s + 1) : (nsteps - 2 - s);
      gnext = *(const uint4*)(G + ((size_t)trn * 32 + jb0 + gc) * 1024 + go * 8);
    }
    // tagged poll: wave wv owns qwords {i*512 + wv*64 + ln : i<8}
    {
      const unsigned long long* src = hstT + ((size_t)rb * 2 + d) * 4096;
      const unsigned expect = (unsigned)(tag_base + s);
      unsigned long long v[8];
      bool ok;
      do {
        ok = true;
#pragma unroll
        for (int i = 0; i < 8; i++)
          v[i] = __hip_atomic_load(src + i * 512 + tid, __ATOMIC_RELAXED, __HIP_MEMORY_SCOPE_AGENT);
#pragma unroll
        for (int i = 0; i < 8; i++) ok = ok && ((unsigned)(v[i] >> 32) == expect);
      } while (!__all(ok));
      // qword q = pair*16 + b -> Hb[b][pair*2]
#pragma unroll
      for (int i = 0; i < 8; i++) {
        int q = i * 512 + tid;
        *(unsigned*)&Hb[q & 15][(q >> 4) * 2] = (unsigned)v[i];
      }
    }
    __syncthreads();
    f32x4 acc0 = {}, acc1 = {};
#pragma unroll
    for (int kk = 0; kk < 16; kk++) {
      bf16x8 b = *(const bf16x8*)&Hb[lb][kk * 32 + lq * 8];
      acc0 = __builtin_amdgcn_mfma_f32_16x16x32_bf16(afrag[0][kk], b, acc0, 0, 0, 0);
      acc1 = __builtin_amdgcn_mfma_f32_16x16x32_bf16(afrag[1][kk], b, acc1, 0, 0, 0);
    }
#pragma unroll
    for (int r = 0; r < 4; r++) {
      Ex[gate][u0 + lq * 4 + r][lb]      = acc0[r];
      Ex[gate][u0 + 16 + lq * 4 + r][lb] = acc1[r];
    }
    __syncthreads();
    // cell: thread -> (batch cb, units j0+cu and j0+cu+32); gates from LDS slice
    {
      const bf16_t* gs = &Gs[s & 1][0];
      const int uA = cu, uB = cu + 32;
      const bf16_t* gA = gs + (uA >> 4) * 1024 + (uA & 15) * 16 + cb;
      const bf16_t* gB = gs + (uB >> 4) * 1024 + (uB & 15) * 16 + cb;
      float giA = Ex[0][uA][cb] + b2f(gA[0]);
      float gfA = Ex[1][uA][cb] + b2f(gA[256]);
      float ggA = Ex[2][uA][cb] + b2f(gA[512]);
      float goA = Ex[3][uA][cb] + b2f(gA[768]);
      float giB = Ex[0][uB][cb] + b2f(gB[0]);
      float gfB = Ex[1][uB][cb] + b2f(gB[256]);
      float ggB = Ex[2][uB][cb] + b2f(gB[512]);
      float goB = Ex[3][uB][cb] + b2f(gB[768]);
      float siA = 1.f / (1.f + expf(-giA));
      float sfA = 1.f / (1.f + expf(-gfA));
      float soA = 1.f / (1.f + expf(-goA));
      float siB = 1.f / (1.f + expf(-giB));
      float sfB = 1.f / (1.f + expf(-gfB));
      float soB = 1.f / (1.f + expf(-goB));
      creg0 = sfA * creg0 + siA * tanhf(ggA);
      creg1 = sfB * creg1 + siB * tanhf(ggB);
      float hA = soA * tanhf(creg0);
      float hB = soB * tanhf(creg1);
      bf16_t hbA = f2b(hA), hbB = f2b(hB);
      XB[t & 15][cb][uA] = hbA;
      XB[t & 15][cb][uB] = hbB;
      if (s + 1 < nsteps) *(uint4*)&Gs[(s + 1) & 1][gc * 1024 + go * 8] = gnext;
      // h pair (u even with u+1 from lane+16) -> tagged 8B agent stores
      unsigned h0 = (unsigned)(unsigned short)hbA;
      unsigned h1 = (unsigned)(unsigned short)hbB;
      unsigned p0 = (unsigned)__shfl_down((int)h0, 16, 64);
      unsigned p1 = (unsigned)__shfl_down((int)h1, 16, 64);
      if ((cu & 1) == 0) {
        unsigned long long tagv =
            ((unsigned long long)(unsigned)(tag_base + s + 1)) << 32;
        unsigned long long* dst =
            hstT + ((size_t)wb * 2 + d) * 4096 + (size_t)((j0 + cu) >> 1) * 16 + cb;
        __hip_atomic_store(dst, tagv | (unsigned long long)(h0 | (p0 << 16)),
                           __ATOMIC_RELAXED, __HIP_MEMORY_SCOPE_AGENT);
        __hip_atomic_store(dst + 256, tagv | (unsigned long long)(h1 | (p1 << 16)),
                           __ATOMIC_RELAXED, __HIP_MEMORY_SCOPE_AGENT);
      }
    }
    // xout flush every 16 steps (coalesced 64B per thread, amortized)
    if ((s & 15) == 15) {
      __syncthreads();
      const int tbase = (d == 0) ? (t - 15) : t;   // 16-aligned in both dirs
      const int row = tid >> 1, half = tid & 1;
      const int tp = row >> 4, b = row & 15;
      const bf16_t* xb = &XB[tp][b][half * 32];
      bf16_t* xo = xout + ((size_t)(tbase + tp) * 16 + b) * 1024 + d * 512 + j0 + half * 32;
      *(uint4*)(xo)      = *(const uint4*)(xb);
      *(uint4*)(xo + 8)  = *(const uint4*)(xb + 8);
      *(uint4*)(xo + 16) = *(const uint4*)(xb + 16);
      *(uint4*)(xo + 24) = *(const uint4*)(xb + 24);
    }
  }
  cst[((size_t)d * 16 + cb) * 512 + j0 + cu]      = creg0;
  cst[((size_t)d * 16 + cb) * 512 + j0 + cu + 32] = creg1;
}

// ---------------- classifier
__global__ void cls_kernel(const bf16_t* __restrict__ X, const float* __restrict__ Wc,
                           const float* __restrict__ bc, float* __restrict__ Lg) {
  int wv = threadIdx.x >> 6, ln = threadIdx.x & 63;
  size_t m = (size_t)blockIdx.x * 4 + wv;
  const bf16_t* xr = X + m * 1024 + ln * 16;
  uint4 v0 = *(const uint4*)xr;
  uint4 v1 = *(const uint4*)(xr + 8);
  float xv[16];
  const unsigned* p0 = (const unsigned*)&v0;
  const unsigned* p1 = (const unsigned*)&v1;
#pragma unroll
  for (int i = 0; i < 4; i++) { xv[2 * i] = blo(p0[i]); xv[2 * i + 1] = bhi(p0[i]); }
#pragma unroll
  for (int i = 0; i < 4; i++) { xv[8 + 2 * i] = blo(p1[i]); xv[8 + 2 * i + 1] = bhi(p1[i]); }
#pragma unroll
  for (int l = 0; l < 6; l++) {
    const float* wr = Wc + l * 1024 + ln * 16;
    float p = 0.f;
#pragma unroll
    for (int i = 0; i < 16; i++) p += xv[i] * wr[i];
#pragma unroll
    for (int off = 32; off; off >>= 1) p += __shfl_xor(p, off, 64);
    if (ln == 0) Lg[m * 6 + l] = p + bc[l];
  }
}

// ---------------- CRF NLL
__global__ void crf_kernel(const float* __restrict__ Lg, const int* __restrict__ attn,
                           const int* __restrict__ labels, const float* __restrict__ start,
                           const float* __restrict__ endw, const float* __restrict__ trans,
                           float* __restrict__ out) {
  int b = blockIdx.x, ln = threadIdx.x;
  __shared__ float str[36];
  __shared__ int tg[1024];
  __shared__ unsigned char mk[1024];
  if (ln < 36) str[ln] = trans[ln];
  for (int t = ln; t < 1024; t += 64) {
    int lab = labels[b * 1024 + t];
    mk[t] = (unsigned char)((attn[b * 1024 + t] != 0) && (lab != -100));
    tg[t] = (lab == -100) ? 0 : lab;
  }
  __syncthreads();
  int j = ln;
  bool act = j < 6;
  float alpha = act ? (start[j] + Lg[(size_t)b * 6 + j]) : -1e30f;
  for (int t = 1; t < 1024; t++) {
    float vv[6], mx = -1e30f;
#pragma unroll
    for (int i = 0; i < 6; i++) {
      float ai = __shfl(alpha, i, 64);
      float v = ai + str[i * 6 + (act ? j : 0)];
      vv[i] = v;
      mx = fmaxf(mx, v);
    }
    float sm = 0.f;
#pragma unroll
    for (int i = 0; i < 6; i++) sm += expf(vv[i] - mx);
    float na = mx + logf(sm) + (act ? Lg[((size_t)t * 16 + b) * 6 + j] : 0.f);
    if (mk[t] && act) alpha = na;
  }
  float z = act ? (alpha + endw[j]) : -1e30f;
  float zm = z;
#pragma unroll
  for (int i = 0; i < 6; i++) zm = fmaxf(zm, __shfl(z, i, 64));
  float zs = act ? expf(z - zm) : 0.f;
  float tot = 0.f;
#pragma unroll
  for (int i = 0; i < 6; i++) tot += __shfl(zs, i, 64);
  float den = zm + logf(tot);
  if (ln == 0) {
    float score = start[tg[0]] + Lg[(size_t)b * 6 + tg[0]];
    int prev = tg[0];
    for (int t = 1; t < 1024; t++) {
      if (mk[t]) {
        score += str[prev * 6 + tg[t]] + Lg[((size_t)t * 16 + b) * 6 + tg[t]];
        prev = tg[t];
      }
    }
    score += endw[prev];
    atomicAdd(out, (den - score) * (1.0f / 16.0f));
  }
}

// ---------------------------------------------------------------------------
extern "C" void kernel_launch(void* const* d_in, const int* in_sizes, int n_in,
                              void* d_out, int out_size, void* d_ws, size_t ws_size,
                              hipStream_t stream) {
  const float* emb    = (const float*)d_in[0];
  const int*   attn   = (const int*)d_in[1];
  const int*   labels = (const int*)d_in[2];
  const float* convw  = (const float*)d_in[3];
  const float* convb  = (const float*)d_in[4];
  const float* bng    = (const float*)d_in[5];
  const float* bnb    = (const float*)d_in[6];
  const float* bnm    = (const float*)d_in[7];
  const float* bnv    = (const float*)d_in[8];
  const float* wih    = (const float*)d_in[9];
  const float* whh    = (const float*)d_in[10];
  const float* bih    = (const float*)d_in[11];
  const float* bhh    = (const float*)d_in[12];
  const float* clsw   = (const float*)d_in[13];
  const float* clsb   = (const float*)d_in[14];
  const float* crfs   = (const float*)d_in[15];
  const float* crfe   = (const float*)d_in[16];
  const float* crft   = (const float*)d_in[17];
  (void)in_sizes; (void)n_in; (void)out_size; (void)ws_size;

  char* w = (char*)d_ws;
  auto alloc = [&](size_t bytes) { char* p = w; w += (bytes + 255) & ~(size_t)255; return p; };
  bf16_t* emb_pad = (bf16_t*)alloc(16ul * 1028 * 1024 * 2);
  bf16_t* wconv   = (bf16_t*)alloc(1024ul * 5120 * 2);
  float*  bn_a    = (float*)alloc(4096);
  float*  bn_d    = (float*)alloc(4096);
  bf16_t* wihb    = (bf16_t*)alloc(3ul * 2 * 2048 * 1024 * 2);
  bf16_t* xA      = (bf16_t*)alloc(16384ul * 1024 * 2);
  bf16_t* xB      = (bf16_t*)alloc(16384ul * 1024 * 2);
  bf16_t* gfw     = (bf16_t*)alloc(512ul * 32 * 1024 * 2);
  bf16_t* gbw     = (bf16_t*)alloc(512ul * 32 * 1024 * 2);
  unsigned long long* hstT = (unsigned long long*)alloc(2ul * 2 * 4096 * 8);
  float*  cst     = (float*)alloc(2ul * 16 * 512 * 4);
  float*  lgt     = (float*)alloc(16384ul * 6 * 4);

  hipMemsetAsync(d_out, 0, 4, stream);

  embed_pad_k<<<16448, 256, 0, stream>>>(emb, emb_pad);
  convw_cvt_k<<<4096, 256, 0, stream>>>(convw, wconv);
  bnfold_k<<<4, 256, 0, stream>>>(convb, bng, bnb, bnm, bnv, bn_a, bn_d);
  wihcvt_k<<<12288, 256, 0, stream>>>(wih, wihb);

  conv_gemm<<<128 * 8, 256, 0, stream>>>(emb_pad, wconv, bn_a, bn_d, xA);

  bf16_t* xin = xA;
  bf16_t* xout = xB;
  for (int l = 0; l < 3; l++) {
    hipMemsetAsync(hstT, 0, 2ul * 2 * 4096 * 8, stream);
    hipMemsetAsync(cst, 0, 2ul * 16 * 512 * 4, stream);
    for (int c = 0; c < 2; c++) {
      int t0f = c * 512, t0b = (1 - c) * 512;
      gemm_gates<<<64 * 16, 256, 0, stream>>>(
          xin + (size_t)t0f * 16 * 1024, wihb + ((size_t)l * 2 + 0) * 2048 * 1024,
          bih + (l * 2 + 0) * 2048, bhh + (l * 2 + 0) * 2048, gfw);
      gemm_gates<<<64 * 16, 256, 0, stream>>>(
          xin + (size_t)t0b * 16 * 1024, wihb + ((size_t)l * 2 + 1) * 2048 * 1024,
          bih + (l * 2 + 1) * 2048, bhh + (l * 2 + 1) * 2048, gbw);
      rec_kernel<<<16, 512, 0, stream>>>(whh + (size_t)l * 2 * 2048 * 512,
                                         gfw, gbw, xout, hstT, cst, t0f, t0b, 512, c * 512);
    }
    bf16_t* tmp = xin; xin = xout; xout = tmp;
  }

  cls_kernel<<<4096, 256, 0, stream>>>(xin, clsw, clsb, lgt);
  crf_kernel<<<16, 64, 0, stream>>>(lgt, attn, labels, crfs, crfe, crft, (float*)d_out);
}